// Round 2
// baseline (547.470 us; speedup 1.0000x reference)
//
#include <hip/hip_runtime.h>

constexpr int NUM_TOKENS   = 8192;
constexpr int NUM_HEADS    = 32;
constexpr int NUM_KV_HEADS = 8;
constexpr int HEAD         = 128;
constexpr int ROW   = NUM_HEADS*HEAD + 2*NUM_KV_HEADS*HEAD;  // 6144
constexpr int KOFF  = NUM_HEADS*HEAD;                        // 4096
constexpr int VOFF  = KOFF + NUM_KV_HEADS*HEAD;              // 5120
constexpr float RMS_EPS = 1e-6f;
// log2(10000) = 13.287712379549449
constexpr float LOG2_BASE_OVER_HALF = 13.287712379549449f / 64.0f;

__global__ __launch_bounds__(256) void qknorm_rope_kv(
    const float* __restrict__ qkv,
    const int*   __restrict__ positions,
    const int*   __restrict__ slots,
    const float* __restrict__ qw,
    const float* __restrict__ kw,
    float* __restrict__ q_out,   // [T][32][128]
    float* __restrict__ k_out,   // [T][8][128]
    float* __restrict__ v_out,   // [T][8][128]
    float* __restrict__ kcache,  // [16384][8][128]
    float* __restrict__ vcache)  // [16384][8][128]
{
    const int t    = blockIdx.x;
    const int tid  = threadIdx.x;
    const int lane = tid & 63;
    const int wave = tid >> 6;

    __shared__ float s_cos[64];
    __shared__ float s_sin[64];
    if (tid < 64) {
        const float pos = (float)positions[t];
        const float inv_freq = exp2f(-(float)tid * LOG2_BASE_OVER_HALF);
        float s, c;
        sincosf(pos * inv_freq, &s, &c);
        s_cos[tid] = c;
        s_sin[tid] = s;
    }
    __syncthreads();

    const int slot = slots[t];
    const float* __restrict__ row = qkv + (size_t)t * ROW;

    // Each lane owns elements e0, e0+1 of a head (float2). Partner element
    // e^64 lives at lane^32 under this layout.
    const int e0 = lane * 2;
    const float c0  = s_cos[e0 & 63];
    const float c1  = s_cos[(e0 + 1) & 63];
    const float sn0 = s_sin[e0 & 63];
    const float sn1 = s_sin[(e0 + 1) & 63];
    const float sgn = (lane < 32) ? -1.0f : 1.0f;  // x1*c - x2*s  |  x2*c + x1*s

    const float2 qw2 = *(const float2*)(qw + e0);
    const float2 kw2 = *(const float2*)(kw + e0);

    // ---- Q heads: 32 heads / 4 waves = 8 iters ----
    for (int h = wave; h < NUM_HEADS; h += 4) {
        float2 x = *(const float2*)(row + h*HEAD + e0);
        float ss = x.x*x.x + x.y*x.y;
        #pragma unroll
        for (int m = 1; m < 64; m <<= 1) ss += __shfl_xor(ss, m, 64);
        const float scale = rsqrtf(ss * (1.0f/HEAD) + RMS_EPS);
        const float n0 = x.x * scale * qw2.x;
        const float n1 = x.y * scale * qw2.y;
        const float p0 = __shfl_xor(n0, 32, 64);
        const float p1 = __shfl_xor(n1, 32, 64);
        float2 o;
        o.x = fmaf(sgn * p0, sn0, n0 * c0);
        o.y = fmaf(sgn * p1, sn1, n1 * c1);
        *(float2*)(q_out + (size_t)t*(NUM_HEADS*HEAD) + h*HEAD + e0) = o;
    }

    // ---- K heads: 8 heads / 4 waves = 2 iters; dual-write out + cache ----
    for (int h = wave; h < NUM_KV_HEADS; h += 4) {
        float2 x = *(const float2*)(row + KOFF + h*HEAD + e0);
        float ss = x.x*x.x + x.y*x.y;
        #pragma unroll
        for (int m = 1; m < 64; m <<= 1) ss += __shfl_xor(ss, m, 64);
        const float scale = rsqrtf(ss * (1.0f/HEAD) + RMS_EPS);
        const float n0 = x.x * scale * kw2.x;
        const float n1 = x.y * scale * kw2.y;
        const float p0 = __shfl_xor(n0, 32, 64);
        const float p1 = __shfl_xor(n1, 32, 64);
        float2 o;
        o.x = fmaf(sgn * p0, sn0, n0 * c0);
        o.y = fmaf(sgn * p1, sn1, n1 * c1);
        *(float2*)(k_out + (size_t)t*(NUM_KV_HEADS*HEAD) + h*HEAD + e0) = o;
        *(float2*)(kcache + (size_t)slot*(NUM_KV_HEADS*HEAD) + h*HEAD + e0) = o;
    }

    // ---- V: pure copy, 1024 floats = 256 lanes x float4 ----
    {
        float4 x = *(const float4*)(row + VOFF + tid*4);
        *(float4*)(v_out  + (size_t)t   *(NUM_KV_HEADS*HEAD) + tid*4) = x;
        *(float4*)(vcache + (size_t)slot*(NUM_KV_HEADS*HEAD) + tid*4) = x;
    }
}

extern "C" void kernel_launch(void* const* d_in, const int* in_sizes, int n_in,
                              void* d_out, int out_size, void* d_ws, size_t ws_size,
                              hipStream_t stream) {
    const float* qkv       = (const float*)d_in[0];
    const int*   positions = (const int*)  d_in[1];
    const int*   slots     = (const int*)  d_in[2];
    const float* qw        = (const float*)d_in[3];
    const float* kw        = (const float*)d_in[4];
    const float* kv_cache  = (const float*)d_in[5];

    float* out    = (float*)d_out;
    float* q_out  = out;
    float* k_out  = q_out + (size_t)NUM_TOKENS * NUM_HEADS    * HEAD;
    float* v_out  = k_out + (size_t)NUM_TOKENS * NUM_KV_HEADS * HEAD;
    float* cache_out = v_out + (size_t)NUM_TOKENS * NUM_KV_HEADS * HEAD;

    const size_t cache_elems = (size_t)2 * 1024 * 16 * NUM_KV_HEADS * HEAD;  // 2*16384*1024

    // Copy whole cache to output first (d_out is re-poisoned every call),
    // then the kernel scatters k/v into it. Same stream => ordered.
    hipMemcpyAsync(cache_out, kv_cache, cache_elems * sizeof(float),
                   hipMemcpyDeviceToDevice, stream);

    float* kcache = cache_out;
    float* vcache = cache_out + cache_elems / 2;

    qknorm_rope_kv<<<NUM_TOKENS, 256, 0, stream>>>(
        qkv, positions, slots, qw, kw, q_out, k_out, v_out, kcache, vcache);
}